// Round 2
// baseline (292.076 us; speedup 1.0000x reference)
//
#include <hip/hip_runtime.h>
#include <hip/hip_bf16.h>

#define B_ 4
#define N_ 512
#define D_ 512
#define H_ 8
#define DK_ 64

// ---------------------------------------------------------------------------
// Generic tiled GEMM + bias: C[M,Nc] = A[M,K] @ W[K,Nc] + bias
// blockIdx.z selects one of up to 3 independent (A,W,bias,C) sets so the three
// QKV projections run in a single 768-block launch (3 blocks/CU).
// ---------------------------------------------------------------------------
struct Gemm3Args {
    const float* A[3];
    const float* W[3];
    const float* bias[3];
    float* C[3];
};

__global__ __launch_bounds__(256) void gemm_bias_k(Gemm3Args ga, int M, int K, int Nc)
{
    const int z = blockIdx.z;
    const float* __restrict__ A = ga.A[z];
    const float* __restrict__ W = ga.W[z];
    const float* __restrict__ bias = ga.bias[z];
    float* __restrict__ C = ga.C[z];

    __shared__ float As[16][64];   // As[kk][m] (transposed A tile)
    __shared__ float Bs[16][64];   // Bs[kk][n]

    const int t = threadIdx.x;
    const int tx = t & 15, ty = t >> 4;
    const int row0 = blockIdx.y << 6, col0 = blockIdx.x << 6;
    const int ar = t >> 2, ak4 = (t & 3) << 2;       // A stage: row ar, k-offset ak4
    const int bk = t >> 4, bn4 = (t & 15) << 2;      // B stage: k row bk, col bn4

    float acc[4][4] = {};
    for (int k0 = 0; k0 < K; k0 += 16) {
        float4 a4 = *(const float4*)(A + (size_t)(row0 + ar) * K + k0 + ak4);
        float4 b4 = *(const float4*)(W + (size_t)(k0 + bk) * Nc + col0 + bn4);
        As[ak4 + 0][ar] = a4.x;
        As[ak4 + 1][ar] = a4.y;
        As[ak4 + 2][ar] = a4.z;
        As[ak4 + 3][ar] = a4.w;
        *(float4*)&Bs[bk][bn4] = b4;
        __syncthreads();
#pragma unroll
        for (int kk = 0; kk < 16; ++kk) {
            const float4 av = *(const float4*)&As[kk][ty << 2];
            const float4 bv = *(const float4*)&Bs[kk][tx << 2];
            const float a0 = av.x, a1 = av.y, a2 = av.z, a3 = av.w;
            const float b0 = bv.x, b1 = bv.y, b2 = bv.z, b3 = bv.w;
            acc[0][0] = fmaf(a0, b0, acc[0][0]); acc[0][1] = fmaf(a0, b1, acc[0][1]);
            acc[0][2] = fmaf(a0, b2, acc[0][2]); acc[0][3] = fmaf(a0, b3, acc[0][3]);
            acc[1][0] = fmaf(a1, b0, acc[1][0]); acc[1][1] = fmaf(a1, b1, acc[1][1]);
            acc[1][2] = fmaf(a1, b2, acc[1][2]); acc[1][3] = fmaf(a1, b3, acc[1][3]);
            acc[2][0] = fmaf(a2, b0, acc[2][0]); acc[2][1] = fmaf(a2, b1, acc[2][1]);
            acc[2][2] = fmaf(a2, b2, acc[2][2]); acc[2][3] = fmaf(a2, b3, acc[2][3]);
            acc[3][0] = fmaf(a3, b0, acc[3][0]); acc[3][1] = fmaf(a3, b1, acc[3][1]);
            acc[3][2] = fmaf(a3, b2, acc[3][2]); acc[3][3] = fmaf(a3, b3, acc[3][3]);
        }
        __syncthreads();
    }
    const float4 bb = *(const float4*)(bias + col0 + (tx << 2));
#pragma unroll
    for (int i = 0; i < 4; ++i) {
        float4 o;
        o.x = acc[i][0] + bb.x;
        o.y = acc[i][1] + bb.y;
        o.z = acc[i][2] + bb.z;
        o.w = acc[i][3] + bb.w;
        *(float4*)(C + (size_t)(row0 + (ty << 2) + i) * Nc + col0 + (tx << 2)) = o;
    }
}

// ---------------------------------------------------------------------------
// Geometry kernel: per (b,i,j) compute the 64-dim sin/cos box embedding, dot
// with Wg -> 8 head weights, relu, clip, log; fold mask (mask==0 -> -1e9).
// Writes logw[B,H,N,N] fp32.
// ---------------------------------------------------------------------------
__global__ __launch_bounds__(256) void geo_k(
    const float* __restrict__ box, const int* __restrict__ mask,
    const float* __restrict__ Wg, const float* __restrict__ bg,
    float* __restrict__ logw)
{
    __shared__ float WgL[64][8];
    __shared__ float bgL[8];
    const int t = threadIdx.x;
    if (t < 128) ((float4*)&WgL[0][0])[t] = ((const float4*)Wg)[t];
    if (t < 8) bgL[t] = bg[t];
    __syncthreads();

    const size_t gid = (size_t)blockIdx.x * 256 + t;
    const int j = (int)(gid & (N_ - 1));
    const int i = (int)((gid >> 9) & (N_ - 1));
    const int b = (int)(gid >> 18);

    const float* bip = box + ((size_t)b * N_ + i) * 4;
    const float xi0 = bip[0], xi1 = bip[1], yi0 = bip[2], yi1 = bip[3];
    const float4 bj = *(const float4*)(box + ((size_t)b * N_ + j) * 4);

    const float cxi = (xi0 + xi1) * 0.5f, cyi = (yi0 + yi1) * 0.5f;
    const float wi = xi1 - xi0 + 1.0f, hi = yi1 - yi0 + 1.0f;
    const float cxj = (bj.x + bj.y) * 0.5f, cyj = (bj.z + bj.w) * 0.5f;
    const float wj = bj.y - bj.x + 1.0f, hj = bj.w - bj.z + 1.0f;

    float pos[4];
    pos[0] = __logf(fmaxf(fabsf((cxi - cxj) / wi), 1e-3f));
    pos[1] = __logf(fmaxf(fabsf((cyi - cyj) / hi), 1e-3f));
    pos[2] = __logf(wi / wj);
    pos[3] = __logf(hi / hj);

    // 1 / 1000^(f/8), f = 0..7
    const float dimr[8] = {1.0f, 0.421696503f, 0.177827941f, 0.0749894209f,
                           0.0316227766f, 0.0133352143f, 0.00562341325f, 0.00237137371f};

    float acc[8] = {0.f, 0.f, 0.f, 0.f, 0.f, 0.f, 0.f, 0.f};
#pragma unroll
    for (int p = 0; p < 4; ++p) {
        const float base = 100.0f * pos[p];
#pragma unroll
        for (int f = 0; f < 8; ++f) {
            float s, c;
            __sincosf(base * dimr[f], &s, &c);
            const int g = p * 8 + f;
            const float4 wa = *(const float4*)&WgL[g][0];
            const float4 wb = *(const float4*)&WgL[g][4];
            const float4 ca = *(const float4*)&WgL[g + 32][0];
            const float4 cb = *(const float4*)&WgL[g + 32][4];
            acc[0] = fmaf(s, wa.x, fmaf(c, ca.x, acc[0]));
            acc[1] = fmaf(s, wa.y, fmaf(c, ca.y, acc[1]));
            acc[2] = fmaf(s, wa.z, fmaf(c, ca.z, acc[2]));
            acc[3] = fmaf(s, wa.w, fmaf(c, ca.w, acc[3]));
            acc[4] = fmaf(s, wb.x, fmaf(c, cb.x, acc[4]));
            acc[5] = fmaf(s, wb.y, fmaf(c, cb.y, acc[5]));
            acc[6] = fmaf(s, wb.z, fmaf(c, cb.z, acc[6]));
            acc[7] = fmaf(s, wb.w, fmaf(c, cb.w, acc[7]));
        }
    }

    const int mk = mask[gid];
#pragma unroll
    for (int h = 0; h < 8; ++h) {
        const float gw = acc[h] + bgL[h];
        const float lw = (mk == 0) ? -1e9f : __logf(fmaxf(gw, 1e-6f));
        logw[(((size_t)b * H_ + h) * N_ + i) * N_ + j] = lw;
    }
}

// ---------------------------------------------------------------------------
// Fused flash-style attention. One block = one (b, h, 64-row q tile).
// 256 threads, 4x4 register micro-tile; all hot LDS reads are aligned
// ds_read_b128 with <=2-way bank aliasing (free). LDS = exactly 64 KB.
// ---------------------------------------------------------------------------
__global__ __launch_bounds__(256) void attn_k(
    const float* __restrict__ qb, const float* __restrict__ kb,
    const float* __restrict__ vb, const float* __restrict__ logw,
    float* __restrict__ ob)
{
    __shared__ float Qst[64][64];   // [d][r]   (Q tile, transposed)
    __shared__ float Kst[64][64];   // [d][k]   (K chunk, transposed)
    __shared__ float Vs[64][64];    // [k][d]   (V chunk, natural)
    __shared__ float Pst[64][64];   // [k][r]   (P chunk, transposed)

    const int t = threadIdx.x;
    const int tx = t & 15, ty = t >> 4;
    const int bx = blockIdx.x;
    const int qt = bx & 7;
    const int h = (bx >> 3) & 7;
    const int b = bx >> 6;
    const int q0 = qt << 6;

    // stage Q tile (transposed)
#pragma unroll
    for (int it = 0; it < 4; ++it) {
        const int idx = (it << 8) + t;
        const int r = idx >> 4, c4 = (idx & 15) << 2;
        const float4 f = *(const float4*)(qb + (((size_t)b * N_ + q0 + r) * H_ + h) * DK_ + c4);
        Qst[c4 + 0][r] = f.x;
        Qst[c4 + 1][r] = f.y;
        Qst[c4 + 2][r] = f.z;
        Qst[c4 + 3][r] = f.w;
    }

    float m[4] = {-1e30f, -1e30f, -1e30f, -1e30f};
    float l[4] = {0.f, 0.f, 0.f, 0.f};
    float o_[4][4] = {};

    const float* lwbase = logw + (((size_t)b * H_ + h) * N_ + q0) * N_;

    for (int k0 = 0; k0 < N_; k0 += 64) {
        __syncthreads();   // previous PV reads of Vs/Pst done before overwrite
        // stage K chunk (transposed) + V chunk (natural)
#pragma unroll
        for (int it = 0; it < 4; ++it) {
            const int idx = (it << 8) + t;
            const int r = idx >> 4, c4 = (idx & 15) << 2;
            const size_t rowoff = (((size_t)b * N_ + k0 + r) * H_ + h) * DK_ + c4;
            const float4 f = *(const float4*)(kb + rowoff);
            Kst[c4 + 0][r] = f.x;
            Kst[c4 + 1][r] = f.y;
            Kst[c4 + 2][r] = f.z;
            Kst[c4 + 3][r] = f.w;
            const float4 g = *(const float4*)(vb + rowoff);
            *(float4*)&Vs[r][c4] = g;
        }
        __syncthreads();

        // S = Q K^T over this chunk (4x4 per thread)
        float s_[4][4] = {};
#pragma unroll 16
        for (int d = 0; d < 64; ++d) {
            const float4 qv = *(const float4*)&Qst[d][ty << 2];
            const float4 kv = *(const float4*)&Kst[d][tx << 2];
            s_[0][0] = fmaf(qv.x, kv.x, s_[0][0]); s_[0][1] = fmaf(qv.x, kv.y, s_[0][1]);
            s_[0][2] = fmaf(qv.x, kv.z, s_[0][2]); s_[0][3] = fmaf(qv.x, kv.w, s_[0][3]);
            s_[1][0] = fmaf(qv.y, kv.x, s_[1][0]); s_[1][1] = fmaf(qv.y, kv.y, s_[1][1]);
            s_[1][2] = fmaf(qv.y, kv.z, s_[1][2]); s_[1][3] = fmaf(qv.y, kv.w, s_[1][3]);
            s_[2][0] = fmaf(qv.z, kv.x, s_[2][0]); s_[2][1] = fmaf(qv.z, kv.y, s_[2][1]);
            s_[2][2] = fmaf(qv.z, kv.z, s_[2][2]); s_[2][3] = fmaf(qv.z, kv.w, s_[2][3]);
            s_[3][0] = fmaf(qv.w, kv.x, s_[3][0]); s_[3][1] = fmaf(qv.w, kv.y, s_[3][1]);
            s_[3][2] = fmaf(qv.w, kv.z, s_[3][2]); s_[3][3] = fmaf(qv.w, kv.w, s_[3][3]);
        }

        // online softmax per row (rows 4*ty+i; reduce across the 16 tx lanes)
#pragma unroll
        for (int i = 0; i < 4; ++i) {
            const float4 lw = *(const float4*)(lwbase + (size_t)((ty << 2) + i) * N_ + k0 + (tx << 2));
            const float sv0 = fmaf(s_[i][0], 0.125f, lw.x);
            const float sv1 = fmaf(s_[i][1], 0.125f, lw.y);
            const float sv2 = fmaf(s_[i][2], 0.125f, lw.z);
            const float sv3 = fmaf(s_[i][3], 0.125f, lw.w);
            float cm = fmaxf(fmaxf(sv0, sv1), fmaxf(sv2, sv3));
            cm = fmaxf(cm, __shfl_xor(cm, 1));
            cm = fmaxf(cm, __shfl_xor(cm, 2));
            cm = fmaxf(cm, __shfl_xor(cm, 4));
            cm = fmaxf(cm, __shfl_xor(cm, 8));
            const float mn = fmaxf(m[i], cm);
            const float sc = __expf(m[i] - mn);
            const float p0 = __expf(sv0 - mn);
            const float p1 = __expf(sv1 - mn);
            const float p2 = __expf(sv2 - mn);
            const float p3 = __expf(sv3 - mn);
            float ps = (p0 + p1) + (p2 + p3);
            ps += __shfl_xor(ps, 1);
            ps += __shfl_xor(ps, 2);
            ps += __shfl_xor(ps, 4);
            ps += __shfl_xor(ps, 8);
            l[i] = l[i] * sc + ps;
            m[i] = mn;
            o_[i][0] *= sc; o_[i][1] *= sc; o_[i][2] *= sc; o_[i][3] *= sc;
            Pst[(tx << 2) + 0][(ty << 2) + i] = p0;
            Pst[(tx << 2) + 1][(ty << 2) + i] = p1;
            Pst[(tx << 2) + 2][(ty << 2) + i] = p2;
            Pst[(tx << 2) + 3][(ty << 2) + i] = p3;
        }
        __syncthreads();

        // O += P V
#pragma unroll 16
        for (int k = 0; k < 64; ++k) {
            const float4 pv = *(const float4*)&Pst[k][ty << 2];
            const float4 vv = *(const float4*)&Vs[k][tx << 2];
            o_[0][0] = fmaf(pv.x, vv.x, o_[0][0]); o_[0][1] = fmaf(pv.x, vv.y, o_[0][1]);
            o_[0][2] = fmaf(pv.x, vv.z, o_[0][2]); o_[0][3] = fmaf(pv.x, vv.w, o_[0][3]);
            o_[1][0] = fmaf(pv.y, vv.x, o_[1][0]); o_[1][1] = fmaf(pv.y, vv.y, o_[1][1]);
            o_[1][2] = fmaf(pv.y, vv.z, o_[1][2]); o_[1][3] = fmaf(pv.y, vv.w, o_[1][3]);
            o_[2][0] = fmaf(pv.z, vv.x, o_[2][0]); o_[2][1] = fmaf(pv.z, vv.y, o_[2][1]);
            o_[2][2] = fmaf(pv.z, vv.z, o_[2][2]); o_[2][3] = fmaf(pv.z, vv.w, o_[2][3]);
            o_[3][0] = fmaf(pv.w, vv.x, o_[3][0]); o_[3][1] = fmaf(pv.w, vv.y, o_[3][1]);
            o_[3][2] = fmaf(pv.w, vv.z, o_[3][2]); o_[3][3] = fmaf(pv.w, vv.w, o_[3][3]);
        }
    }

#pragma unroll
    for (int i = 0; i < 4; ++i) {
        const float inv = 1.0f / l[i];
        float4 w;
        w.x = o_[i][0] * inv;
        w.y = o_[i][1] * inv;
        w.z = o_[i][2] * inv;
        w.w = o_[i][3] * inv;
        *(float4*)(ob + (((size_t)b * N_ + q0 + (ty << 2) + i) * H_ + h) * DK_ + (tx << 2)) = w;
    }
}

// ---------------------------------------------------------------------------
extern "C" void kernel_launch(void* const* d_in, const int* in_sizes, int n_in,
                              void* d_out, int out_size, void* d_ws, size_t ws_size,
                              hipStream_t stream)
{
    (void)in_sizes; (void)n_in; (void)out_size; (void)ws_size;

    const float* q_in = (const float*)d_in[0];
    const float* k_in = (const float*)d_in[1];
    const float* v_in = (const float*)d_in[2];
    const float* box  = (const float*)d_in[3];
    const int*   mask = (const int*)d_in[4];
    const float* Wq = (const float*)d_in[5];
    const float* bq = (const float*)d_in[6];
    const float* Wk = (const float*)d_in[7];
    const float* bk_in = (const float*)d_in[8];
    const float* Wv = (const float*)d_in[9];
    const float* bv = (const float*)d_in[10];
    const float* Wo = (const float*)d_in[11];
    const float* bo = (const float*)d_in[12];
    const float* Wg = (const float*)d_in[13];
    const float* bg = (const float*)d_in[14];
    float* out = (float*)d_out;

    char* ws = (char*)d_ws;
    float* qb   = (float*)(ws);                        // 4 MB
    float* kb   = (float*)(ws + (4u << 20));           // 4 MB
    float* vb   = (float*)(ws + (8u << 20));           // 4 MB
    float* ob   = (float*)(ws + (12u << 20));          // 4 MB
    float* logw = (float*)(ws + (16u << 20));          // 32 MB

    // 1) QKV projections (one launch, grid.z = 3)
    Gemm3Args g1;
    g1.A[0] = q_in;  g1.A[1] = k_in;  g1.A[2] = v_in;
    g1.W[0] = Wq;    g1.W[1] = Wk;    g1.W[2] = Wv;
    g1.bias[0] = bq; g1.bias[1] = bk_in; g1.bias[2] = bv;
    g1.C[0] = qb;    g1.C[1] = kb;    g1.C[2] = vb;
    dim3 grid1(D_ / 64, (B_ * N_) / 64, 3);
    gemm_bias_k<<<grid1, 256, 0, stream>>>(g1, B_ * N_, D_, D_);

    // 2) geometry -> logw (mask folded in)
    geo_k<<<dim3((B_ * N_ * N_) / 256), 256, 0, stream>>>(box, mask, Wg, bg, logw);

    // 3) fused attention
    attn_k<<<dim3(B_ * H_ * (N_ / 64)), 256, 0, stream>>>(qb, kb, vb, logw, ob);

    // 4) output projection
    Gemm3Args g2 = {};
    g2.A[0] = ob; g2.W[0] = Wo; g2.bias[0] = bo; g2.C[0] = out;
    dim3 grid2(D_ / 64, (B_ * N_) / 64, 1);
    gemm_bias_k<<<grid2, 256, 0, stream>>>(g2, B_ * N_, D_, D_);
}

// Round 3
// 96.193 us; speedup vs baseline: 3.0364x; 3.0364x over previous
//
#include <hip/hip_runtime.h>
#include <hip/hip_bf16.h>

#define Bq 4
#define Nn 512
#define Dd 512
#define Hh 8
#define DKk 64

typedef __bf16 bf16x8 __attribute__((ext_vector_type(8)));
typedef float f32x4 __attribute__((ext_vector_type(4)));
typedef unsigned short u16x8 __attribute__((ext_vector_type(8)));

// fp32 -> bf16 RNE via bit trick (no NaN inputs in this problem)
static __device__ __forceinline__ unsigned short f2bf(float f) {
    unsigned int u = __float_as_uint(f);
    unsigned int r = (u + 0x7FFFu + ((u >> 16) & 1u)) >> 16;
    return (unsigned short)r;
}

// ---------------------------------------------------------------------------
// Weight prep: W[k][n] fp32 -> Wt[n][k] bf16 for all 4 projection matrices.
// ---------------------------------------------------------------------------
__global__ __launch_bounds__(256) void wt_prep_k(
    const float* __restrict__ W0, const float* __restrict__ W1,
    const float* __restrict__ W2, const float* __restrict__ W3,
    unsigned short* __restrict__ Wt)
{
    __shared__ float Ws[64][65];
    const int z = blockIdx.z;
    const float* W = (z == 0) ? W0 : (z == 1) ? W1 : (z == 2) ? W2 : W3;
    const int k0 = blockIdx.x << 6, n0 = blockIdx.y << 6;
    const int t = threadIdx.x;
#pragma unroll
    for (int it = 0; it < 4; ++it) {
        const int idx = (it << 8) + t;
        const int r = idx >> 4, c4 = (idx & 15) << 2;
        const float4 w4 = *(const float4*)(W + (size_t)(k0 + r) * Dd + n0 + c4);
        Ws[r][c4 + 0] = w4.x; Ws[r][c4 + 1] = w4.y;
        Ws[r][c4 + 2] = w4.z; Ws[r][c4 + 3] = w4.w;
    }
    __syncthreads();
    unsigned short* Wtz = Wt + (size_t)z * Dd * Dd;
#pragma unroll
    for (int it = 0; it < 2; ++it) {
        const int idx = (it << 8) + t;
        const int n = idx >> 3, k8 = (idx & 7) << 3;
        u16x8 o;
#pragma unroll
        for (int jj = 0; jj < 8; ++jj) o[jj] = f2bf(Ws[k8 + jj][n]);
        *(u16x8*)(Wtz + (size_t)(n0 + n) * Dd + k0 + k8) = o;
    }
}

// ---------------------------------------------------------------------------
// bf16 MFMA GEMM: C = A[2048,512] @ W[512,512] + bias, 64x64 tile, 4 waves.
// Wave w computes rows w*16..w*16+15 x all 64 cols (4 col-fragments).
// C addressing: addr = (row>>9)*N*D + (row&511)*ns + col*cs  (V writes [b,h,d,n]).
// ---------------------------------------------------------------------------
struct GemmArgs {
    const void* A[3];
    const unsigned short* Wt[3];
    const float* bias[3];
    void* C[3];
    int ns[3];
    int cs[3];
};

template<bool A_BF16, bool C_BF16>
__global__ __launch_bounds__(256) void gemm_mfma_k(GemmArgs ga)
{
    __shared__ unsigned short Alds[64][40];   // [m][k], +8 pad: 2-way banks on frag reads
    __shared__ unsigned short Blds[64][40];   // [n][k]
    const int z = blockIdx.z;
    const int t = threadIdx.x;
    const int l = t & 63, wq = t >> 6;
    const int row0 = blockIdx.y << 6, col0 = blockIdx.x << 6;
    const unsigned short* Wt = ga.Wt[z];
    const int lr = t >> 2, lc8 = (t & 3) << 3;
    const int lrow = l & 15, lgrp = l >> 4;

    f32x4 acc[4];
#pragma unroll
    for (int i = 0; i < 4; ++i) acc[i] = (f32x4){0.f, 0.f, 0.f, 0.f};

    const int arow = wq * 16 + lrow;
    const int aoff = lgrp << 3;

    for (int k0 = 0; k0 < Dd; k0 += 32) {
        u16x8 a8;
        if constexpr (A_BF16) {
            a8 = *(const u16x8*)((const unsigned short*)ga.A[z] + (size_t)(row0 + lr) * Dd + k0 + lc8);
        } else {
            const float* Af = (const float*)ga.A[z] + (size_t)(row0 + lr) * Dd + k0 + lc8;
            const float4 f1 = *(const float4*)Af;
            const float4 f2 = *(const float4*)(Af + 4);
            a8[0] = f2bf(f1.x); a8[1] = f2bf(f1.y); a8[2] = f2bf(f1.z); a8[3] = f2bf(f1.w);
            a8[4] = f2bf(f2.x); a8[5] = f2bf(f2.y); a8[6] = f2bf(f2.z); a8[7] = f2bf(f2.w);
        }
        const u16x8 b8 = *(const u16x8*)(Wt + (size_t)(col0 + lr) * Dd + k0 + lc8);
        __syncthreads();                       // prior tile's LDS reads done
        *(u16x8*)&Alds[lr][lc8] = a8;
        *(u16x8*)&Blds[lr][lc8] = b8;
        __syncthreads();                       // staging visible
        const bf16x8 a = *(const bf16x8*)&Alds[arow][aoff];
#pragma unroll
        for (int nf = 0; nf < 4; ++nf) {
            const bf16x8 bfr = *(const bf16x8*)&Blds[nf * 16 + lrow][aoff];
            acc[nf] = __builtin_amdgcn_mfma_f32_16x16x32_bf16(a, bfr, acc[nf], 0, 0, 0);
        }
    }

    const float* bias = ga.bias[z];
    const int ns = ga.ns[z], cs = ga.cs[z];
    const int rbase = row0 + wq * 16 + (lgrp << 2);
#pragma unroll
    for (int nf = 0; nf < 4; ++nf) {
        const int colg = col0 + nf * 16 + lrow;
        const float bv = bias[colg];
#pragma unroll
        for (int r = 0; r < 4; ++r) {
            const int rowg = rbase + r;
            const size_t addr = (size_t)(rowg >> 9) * ((size_t)Nn * Dd)
                              + (size_t)(rowg & (Nn - 1)) * ns + (size_t)colg * cs;
            const float v = acc[nf][r] + bv;
            if constexpr (C_BF16) ((unsigned short*)ga.C[z])[addr] = f2bf(v);
            else                  ((float*)ga.C[z])[addr] = v;
        }
    }
}

// ---------------------------------------------------------------------------
// Geometry kernel: per (b,i,j) 32 sincos -> dot with Wg -> relu/clip/log,
// mask folded. p-loop rolled to keep VGPR low; f-loop unrolled with
// compile-time dim_mat constants.
// ---------------------------------------------------------------------------
__global__ __launch_bounds__(256, 4) void geo_k(
    const float* __restrict__ box, const int* __restrict__ mask,
    const float* __restrict__ Wg, const float* __restrict__ bg,
    float* __restrict__ logw)
{
    __shared__ float WgS[64][8];
    __shared__ float bgS[8];
    const int t = threadIdx.x;
    if (t < 128) ((float4*)&WgS[0][0])[t] = ((const float4*)Wg)[t];
    if (t < 8) bgS[t] = bg[t];
    __syncthreads();

    const size_t gid = (size_t)blockIdx.x * 256 + t;
    const int j = (int)(gid & (Nn - 1));
    const int i = (int)((gid >> 9) & (Nn - 1));
    const int b = (int)(gid >> 18);

    const float4 bi = *(const float4*)(box + ((size_t)b * Nn + i) * 4);
    const float4 bj = *(const float4*)(box + ((size_t)b * Nn + j) * 4);

    const float cxi = (bi.x + bi.y) * 0.5f, cyi = (bi.z + bi.w) * 0.5f;
    const float wi = bi.y - bi.x + 1.0f, hi = bi.w - bi.z + 1.0f;
    const float cxj = (bj.x + bj.y) * 0.5f, cyj = (bj.z + bj.w) * 0.5f;
    const float wj = bj.y - bj.x + 1.0f, hj = bj.w - bj.z + 1.0f;

    const float pos0 = __logf(fmaxf(fabsf((cxi - cxj) / wi), 1e-3f));
    const float pos1 = __logf(fmaxf(fabsf((cyi - cyj) / hi), 1e-3f));
    const float pos2 = __logf(wi / wj);
    const float pos3 = __logf(hi / hj);

    const float dimr[8] = {1.0f, 0.421696503f, 0.177827941f, 0.0749894209f,
                           0.0316227766f, 0.0133352143f, 0.00562341325f, 0.00237137371f};

    float acc[8] = {0.f, 0.f, 0.f, 0.f, 0.f, 0.f, 0.f, 0.f};
#pragma unroll 1
    for (int p = 0; p < 4; ++p) {
        const float base = 100.0f * ((p == 0) ? pos0 : (p == 1) ? pos1 : (p == 2) ? pos2 : pos3);
        const int g0 = p << 3;
#pragma unroll
        for (int f = 0; f < 8; ++f) {
            float s, c;
            __sincosf(base * dimr[f], &s, &c);
            const int g = g0 + f;
            const float4 wa = *(const float4*)&WgS[g][0];
            const float4 wb = *(const float4*)&WgS[g][4];
            const float4 ca = *(const float4*)&WgS[g + 32][0];
            const float4 cb = *(const float4*)&WgS[g + 32][4];
            acc[0] = fmaf(s, wa.x, fmaf(c, ca.x, acc[0]));
            acc[1] = fmaf(s, wa.y, fmaf(c, ca.y, acc[1]));
            acc[2] = fmaf(s, wa.z, fmaf(c, ca.z, acc[2]));
            acc[3] = fmaf(s, wa.w, fmaf(c, ca.w, acc[3]));
            acc[4] = fmaf(s, wb.x, fmaf(c, cb.x, acc[4]));
            acc[5] = fmaf(s, wb.y, fmaf(c, cb.y, acc[5]));
            acc[6] = fmaf(s, wb.z, fmaf(c, cb.z, acc[6]));
            acc[7] = fmaf(s, wb.w, fmaf(c, cb.w, acc[7]));
        }
    }

    const int mk = mask[gid];
    const size_t outbase = (size_t)b * Hh * Nn * Nn + (size_t)i * Nn + j;
#pragma unroll
    for (int hh = 0; hh < 8; ++hh) {
        const float gw = acc[hh] + bgS[hh];
        const float lw = (mk == 0) ? -1e9f : __logf(fmaxf(gw, 1e-6f));
        logw[outbase + (size_t)hh * Nn * Nn] = lw;
    }
}

// ---------------------------------------------------------------------------
// Fused flash attention, bf16 MFMA. Block = (b, h, 64 q-rows), 4 waves.
// Wave = 16 q-rows x full 64-k chunk. Q/K in LDS [r][d] (stride 72),
// V pre-transposed in global [b,h,d,n] -> Vlds[d][k] with no LDS transpose.
// P staged bf16 per-wave (wave-local, no barrier needed).
// ---------------------------------------------------------------------------
__global__ __launch_bounds__(256) void attn_k(
    const unsigned short* __restrict__ qb, const unsigned short* __restrict__ kb,
    const unsigned short* __restrict__ vt, const float* __restrict__ logw,
    unsigned short* __restrict__ ob)
{
    __shared__ unsigned short Qlds[64][72];
    __shared__ unsigned short Klds[64][72];
    __shared__ unsigned short Vlds[64][72];
    __shared__ unsigned short Plds[4][16][72];

    const int t = threadIdx.x;
    const int l = t & 63, wq = t >> 6;
    const int bx = blockIdx.x;
    const int qt = bx & 7, h = (bx >> 3) & 7, b = bx >> 6;
    const int q0 = qt << 6;
    const int sr = t >> 3, sc8 = (t & 7) << 3;
    const int lrow = l & 15, lgrp = l >> 4;

    // stage Q tile once
#pragma unroll
    for (int it = 0; it < 2; ++it) {
        const int r = it * 32 + sr;
        const u16x8 v = *(const u16x8*)(qb + (((size_t)b * Nn + q0 + r) * Hh + h) * DKk + sc8);
        *(u16x8*)&Qlds[r][sc8] = v;
    }
    __syncthreads();
    bf16x8 qa[2];
    qa[0] = *(const bf16x8*)&Qlds[wq * 16 + lrow][lgrp * 8];
    qa[1] = *(const bf16x8*)&Qlds[wq * 16 + lrow][32 + lgrp * 8];

    float m[4], lsum[4];
    f32x4 oacc[4];
#pragma unroll
    for (int r = 0; r < 4; ++r) { m[r] = -1e30f; lsum[r] = 0.f; }
#pragma unroll
    for (int fd = 0; fd < 4; ++fd) oacc[fd] = (f32x4){0.f, 0.f, 0.f, 0.f};

    const float* lwp = logw + ((size_t)(b * Hh + h) * Nn + q0 + wq * 16 + lgrp * 4) * Nn;

    for (int k0 = 0; k0 < Nn; k0 += 64) {
        __syncthreads();   // previous chunk's K/V reads complete
#pragma unroll
        for (int it = 0; it < 2; ++it) {
            const int r = it * 32 + sr;
            const u16x8 kv = *(const u16x8*)(kb + (((size_t)b * Nn + k0 + r) * Hh + h) * DKk + sc8);
            *(u16x8*)&Klds[r][sc8] = kv;
            const u16x8 vv = *(const u16x8*)(vt + ((size_t)(b * Hh + h) * DKk + r) * Nn + k0 + sc8);
            *(u16x8*)&Vlds[r][sc8] = vv;
        }
        __syncthreads();

        // S = Q K^T (rows: this wave's 16 q; cols: 64 k of chunk)
        f32x4 sacc[4];
#pragma unroll
        for (int f = 0; f < 4; ++f) sacc[f] = (f32x4){0.f, 0.f, 0.f, 0.f};
#pragma unroll
        for (int ks = 0; ks < 2; ++ks) {
#pragma unroll
            for (int f = 0; f < 4; ++f) {
                const bf16x8 kf = *(const bf16x8*)&Klds[f * 16 + lrow][ks * 32 + lgrp * 8];
                sacc[f] = __builtin_amdgcn_mfma_f32_16x16x32_bf16(qa[ks], kf, sacc[f], 0, 0, 0);
            }
        }

        // logits + online softmax (row r of this lane = q0+wq*16+lgrp*4+r)
        float p[4][4], mx[4];
#pragma unroll
        for (int r = 0; r < 4; ++r) mx[r] = -1e30f;
#pragma unroll
        for (int f = 0; f < 4; ++f) {
            const int colk = k0 + f * 16 + lrow;
#pragma unroll
            for (int r = 0; r < 4; ++r) {
                const float lg = fmaf(sacc[f][r], 0.125f, lwp[(size_t)r * Nn + colk]);
                p[f][r] = lg;
                mx[r] = fmaxf(mx[r], lg);
            }
        }
#pragma unroll
        for (int r = 0; r < 4; ++r) {
            float cm = mx[r];
            cm = fmaxf(cm, __shfl_xor(cm, 1));
            cm = fmaxf(cm, __shfl_xor(cm, 2));
            cm = fmaxf(cm, __shfl_xor(cm, 4));
            cm = fmaxf(cm, __shfl_xor(cm, 8));
            const float mn = fmaxf(m[r], cm);
            const float sc = __expf(m[r] - mn);
            m[r] = mn;
            float ps = 0.f;
#pragma unroll
            for (int f = 0; f < 4; ++f) {
                p[f][r] = __expf(p[f][r] - mn);
                ps += p[f][r];
            }
            ps += __shfl_xor(ps, 1);
            ps += __shfl_xor(ps, 2);
            ps += __shfl_xor(ps, 4);
            ps += __shfl_xor(ps, 8);
            lsum[r] = lsum[r] * sc + ps;
#pragma unroll
            for (int fd = 0; fd < 4; ++fd) oacc[fd][r] *= sc;
        }

        // P -> per-wave LDS (bf16); wave-local dependency, no __syncthreads
#pragma unroll
        for (int f = 0; f < 4; ++f)
#pragma unroll
            for (int r = 0; r < 4; ++r)
                Plds[wq][lgrp * 4 + r][f * 16 + lrow] = f2bf(p[f][r]);

        // O += P V
#pragma unroll
        for (int ks = 0; ks < 2; ++ks) {
            const bf16x8 pa = *(const bf16x8*)&Plds[wq][lrow][ks * 32 + lgrp * 8];
#pragma unroll
            for (int fd = 0; fd < 4; ++fd) {
                const bf16x8 vf = *(const bf16x8*)&Vlds[fd * 16 + lrow][ks * 32 + lgrp * 8];
                oacc[fd] = __builtin_amdgcn_mfma_f32_16x16x32_bf16(pa, vf, oacc[fd], 0, 0, 0);
            }
        }
    }

    // epilogue: normalize, write ob bf16 [b,n,h,d]
#pragma unroll
    for (int r = 0; r < 4; ++r) {
        const float inv = 1.0f / lsum[r];
        const int qrow = q0 + wq * 16 + lgrp * 4 + r;
#pragma unroll
        for (int fd = 0; fd < 4; ++fd) {
            ob[(((size_t)b * Nn + qrow) * Hh + h) * DKk + fd * 16 + lrow] =
                f2bf(oacc[fd][r] * inv);
        }
    }
}

// ---------------------------------------------------------------------------
extern "C" void kernel_launch(void* const* d_in, const int* in_sizes, int n_in,
                              void* d_out, int out_size, void* d_ws, size_t ws_size,
                              hipStream_t stream)
{
    (void)in_sizes; (void)n_in; (void)out_size; (void)ws_size;

    const float* q_in = (const float*)d_in[0];
    const float* k_in = (const float*)d_in[1];
    const float* v_in = (const float*)d_in[2];
    const float* box  = (const float*)d_in[3];
    const int*   mask = (const int*)d_in[4];
    const float* Wq = (const float*)d_in[5];
    const float* bq = (const float*)d_in[6];
    const float* Wk = (const float*)d_in[7];
    const float* bk = (const float*)d_in[8];
    const float* Wv = (const float*)d_in[9];
    const float* bv = (const float*)d_in[10];
    const float* Wo = (const float*)d_in[11];
    const float* bo = (const float*)d_in[12];
    const float* Wg = (const float*)d_in[13];
    const float* bg = (const float*)d_in[14];
    float* out = (float*)d_out;

    char* ws = (char*)d_ws;
    unsigned short* qb = (unsigned short*)(ws);                 // 2 MB  [b,n,h,d]
    unsigned short* kb = (unsigned short*)(ws + (2u  << 20));   // 2 MB  [b,n,h,d]
    unsigned short* vt = (unsigned short*)(ws + (4u  << 20));   // 2 MB  [b,h,d,n]
    unsigned short* ob = (unsigned short*)(ws + (6u  << 20));   // 2 MB  [b,n,h,d]
    unsigned short* Wt = (unsigned short*)(ws + (8u  << 20));   // 2 MB  4x[n][k] bf16
    float*        logw = (float*)(ws + (10u << 20));            // 32 MB [b,h,i,j]

    // 1) transpose+convert all 4 weight matrices
    wt_prep_k<<<dim3(8, 8, 4), 256, 0, stream>>>(Wq, Wk, Wv, Wo, Wt);

    // 2) QKV projections (bf16 MFMA); V written transposed per head
    GemmArgs g1;
    g1.A[0] = q_in; g1.A[1] = k_in; g1.A[2] = v_in;
    g1.Wt[0] = Wt;  g1.Wt[1] = Wt + (size_t)Dd * Dd; g1.Wt[2] = Wt + (size_t)2 * Dd * Dd;
    g1.bias[0] = bq; g1.bias[1] = bk; g1.bias[2] = bv;
    g1.C[0] = qb; g1.C[1] = kb; g1.C[2] = vt;
    g1.ns[0] = Dd; g1.ns[1] = Dd; g1.ns[2] = 1;
    g1.cs[0] = 1;  g1.cs[1] = 1;  g1.cs[2] = Nn;
    gemm_mfma_k<false, true><<<dim3(8, 32, 3), 256, 0, stream>>>(g1);

    // 3) geometry -> logw (mask folded)
    geo_k<<<dim3((Bq * Nn * Nn) / 256), 256, 0, stream>>>(box, mask, Wg, bg, logw);

    // 4) fused attention (bf16 MFMA)
    attn_k<<<dim3(Bq * Hh * (Nn / 64)), 256, 0, stream>>>(qb, kb, vt, logw, ob);

    // 5) output projection (bf16 A, fp32 C)
    GemmArgs g2 = {};
    g2.A[0] = ob; g2.Wt[0] = Wt + (size_t)3 * Dd * Dd; g2.bias[0] = bo; g2.C[0] = out;
    g2.ns[0] = Dd; g2.cs[0] = 1;
    gemm_mfma_k<true, false><<<dim3(8, 32, 1), 256, 0, stream>>>(g2);
}

// Round 5
// 76.921 us; speedup vs baseline: 3.7971x; 1.2505x over previous
//
#include <hip/hip_runtime.h>
#include <hip/hip_bf16.h>

#define Bq 4
#define Nn 512
#define Dd 512
#define Hh 8
#define DKk 64

typedef __bf16 bf16x8 __attribute__((ext_vector_type(8)));
typedef float f32x4 __attribute__((ext_vector_type(4)));
typedef unsigned short u16x8 __attribute__((ext_vector_type(8)));

// fp32 -> bf16 RNE (no NaN inputs here)
static __device__ __forceinline__ unsigned short f2bf(float f) {
    unsigned int u = __float_as_uint(f);
    return (unsigned short)((u + 0x7FFFu + ((u >> 16) & 1u)) >> 16);
}
static __device__ __forceinline__ unsigned short f2h(float f) {
    union { _Float16 h; unsigned short u; } cv;
    cv.h = (_Float16)f;
    return cv.u;
}
static __device__ __forceinline__ float h2f(unsigned short us) {
    union { _Float16 h; unsigned short u; } cv;
    cv.u = us;
    return (float)cv.h;
}

// ---------------------------------------------------------------------------
// Merged kernel: geo (4096 blocks) + QKV bf16-MFMA GEMM (768 blocks), striped
// 16:3 per 19-block group so both run concurrently across the CUs.
// GEMM reads W fp32 directly (coalesced column loads -> bf16 B-frag).
// Q is pre-scaled by 1/8 via scale[z] (exact: power of two).
// ---------------------------------------------------------------------------
struct PreArgs {
    const float* A[3];
    const float* W[3];
    const float* bias[3];
    unsigned short* C[3];
    int ns[3], cs[3];
    float scale[3];
    const float* box;
    const int* mask;
    const float* Wg;
    const float* bg;
    unsigned short* lw;   // fp16 [B,H,N,N]
};

__global__ __launch_bounds__(256) void pre_k(PreArgs pa)
{
    __shared__ __align__(16) char pool[10496];
    const int t = threadIdx.x;
    const int r_ = (int)(blockIdx.x % 19), g_ = (int)(blockIdx.x / 19);

    if (r_ < 16) {
        // ------------------------- geo -------------------------
        float (*WgS)[8] = (float(*)[8])pool;          // [g][h] fp32
        float* bgS = (float*)(pool + 2048);
        if (t < 128) ((float4*)&WgS[0][0])[t] = ((const float4*)pa.Wg)[t];
        if (t < 8) bgS[t] = pa.bg[t];
        __syncthreads();

        const int gb = g_ * 16 + r_;
        const size_t gid = (size_t)gb * 256 + t;
        const int j = (int)(gid & (Nn - 1));
        const int i = (int)((gid >> 9) & (Nn - 1));
        const int b = (int)(gid >> 18);

        const float4 bi = *(const float4*)(pa.box + ((size_t)b * Nn + i) * 4);
        const float4 bj = *(const float4*)(pa.box + ((size_t)b * Nn + j) * 4);
        const float cxi = (bi.x + bi.y) * 0.5f, cyi = (bi.z + bi.w) * 0.5f;
        const float wi = bi.y - bi.x + 1.0f, hi = bi.w - bi.z + 1.0f;
        const float cxj = (bj.x + bj.y) * 0.5f, cyj = (bj.z + bj.w) * 0.5f;
        const float wj = bj.y - bj.x + 1.0f, hj = bj.w - bj.z + 1.0f;

        const float pos0 = __logf(fmaxf(fabsf((cxi - cxj) / wi), 1e-3f));
        const float pos1 = __logf(fmaxf(fabsf((cyi - cyj) / hi), 1e-3f));
        const float pos2 = __logf(wi / wj);
        const float pos3 = __logf(hi / hj);

        const float dimr[8] = {1.0f, 0.421696503f, 0.177827941f, 0.0749894209f,
                               0.0316227766f, 0.0133352143f, 0.00562341325f, 0.00237137371f};

        float acc[8] = {0.f, 0.f, 0.f, 0.f, 0.f, 0.f, 0.f, 0.f};
#pragma unroll 1
        for (int p = 0; p < 4; ++p) {
            const float base = 100.0f * ((p == 0) ? pos0 : (p == 1) ? pos1 : (p == 2) ? pos2 : pos3);
            const int g0 = p << 3;
#pragma unroll
            for (int f = 0; f < 8; ++f) {
                float s, c;
                __sincosf(base * dimr[f], &s, &c);
                const int g = g0 + f;
                const float4 wa = *(const float4*)&WgS[g][0];
                const float4 wb = *(const float4*)&WgS[g][4];
                const float4 ca = *(const float4*)&WgS[g + 32][0];
                const float4 cb = *(const float4*)&WgS[g + 32][4];
                acc[0] = fmaf(s, wa.x, fmaf(c, ca.x, acc[0]));
                acc[1] = fmaf(s, wa.y, fmaf(c, ca.y, acc[1]));
                acc[2] = fmaf(s, wa.z, fmaf(c, ca.z, acc[2]));
                acc[3] = fmaf(s, wa.w, fmaf(c, ca.w, acc[3]));
                acc[4] = fmaf(s, wb.x, fmaf(c, cb.x, acc[4]));
                acc[5] = fmaf(s, wb.y, fmaf(c, cb.y, acc[5]));
                acc[6] = fmaf(s, wb.z, fmaf(c, cb.z, acc[6]));
                acc[7] = fmaf(s, wb.w, fmaf(c, cb.w, acc[7]));
            }
        }

        const int mk = pa.mask[gid];
        const size_t ob_ = (size_t)b * Hh * Nn * Nn + (size_t)i * Nn + j;
#pragma unroll
        for (int hh = 0; hh < 8; ++hh) {
            const float gw = acc[hh] + bgS[hh];
            const float lwv = (mk == 0) ? -60000.0f : __logf(fmaxf(gw, 1e-6f));
            pa.lw[ob_ + (size_t)hh * Nn * Nn] = f2h(lwv);
        }
    } else {
        // ------------------------- qkv gemm -------------------------
        unsigned short (*Alds)[40] = (unsigned short(*)[40])pool;
        unsigned short (*Blds)[40] = (unsigned short(*)[40])(pool + 5120);
        const int qid = g_ * 3 + (r_ - 16);
        const int z = qid % 3, tid = qid / 3;
        const int col0 = (tid & 7) << 6, row0 = (tid >> 3) << 6;
        const float* __restrict__ A = pa.A[z];
        const float* __restrict__ W = pa.W[z];

        const int l = t & 63, wq = t >> 6;
        const int lr = t >> 2, lc8 = (t & 3) << 3;
        const int bn = t & 63, bk8 = (t >> 6) << 3;
        const int lrow = l & 15, lgrp = l >> 4;

        f32x4 acc[4];
#pragma unroll
        for (int nf = 0; nf < 4; ++nf) acc[nf] = (f32x4){0.f, 0.f, 0.f, 0.f};

        for (int k0 = 0; k0 < Dd; k0 += 32) {
            const float* Ap = A + (size_t)(row0 + lr) * Dd + k0 + lc8;
            const float4 f1 = *(const float4*)Ap;
            const float4 f2 = *(const float4*)(Ap + 4);
            u16x8 a8;
            a8[0] = f2bf(f1.x); a8[1] = f2bf(f1.y); a8[2] = f2bf(f1.z); a8[3] = f2bf(f1.w);
            a8[4] = f2bf(f2.x); a8[5] = f2bf(f2.y); a8[6] = f2bf(f2.z); a8[7] = f2bf(f2.w);
            u16x8 b8;
#pragma unroll
            for (int jj = 0; jj < 8; ++jj)
                b8[jj] = f2bf(W[(size_t)(k0 + bk8 + jj) * Dd + col0 + bn]);
            __syncthreads();
            *(u16x8*)&Alds[lr][lc8] = a8;
            *(u16x8*)&Blds[bn][bk8] = b8;
            __syncthreads();
            const bf16x8 a = *(const bf16x8*)&Alds[wq * 16 + lrow][lgrp << 3];
#pragma unroll
            for (int nf = 0; nf < 4; ++nf) {
                const bf16x8 bfr = *(const bf16x8*)&Blds[nf * 16 + lrow][lgrp << 3];
                acc[nf] = __builtin_amdgcn_mfma_f32_16x16x32_bf16(a, bfr, acc[nf], 0, 0, 0);
            }
        }

        const float* bias = pa.bias[z];
        const float scl = pa.scale[z];
        const int ns = pa.ns[z], cs = pa.cs[z];
        const int rbase = row0 + wq * 16 + (lgrp << 2);
#pragma unroll
        for (int nf = 0; nf < 4; ++nf) {
            const int colg = col0 + nf * 16 + lrow;
            const float bv = bias[colg];
#pragma unroll
            for (int r = 0; r < 4; ++r) {
                const int rowg = rbase + r;
                const size_t addr = (size_t)(rowg >> 9) * ((size_t)Nn * Dd)
                                  + (size_t)(rowg & (Nn - 1)) * ns + (size_t)colg * cs;
                pa.C[z][addr] = f2bf((acc[nf][r] + bv) * scl);
            }
        }
    }
}

// ---------------------------------------------------------------------------
// Fused flash attention, bf16 MFMA. Block = (b, h, 64 q-rows), 4 waves.
// K/V/logw register-prefetched one chunk ahead; logw LDS-staged fp16.
// Q pre-scaled by 1/8.
// ---------------------------------------------------------------------------
__global__ __launch_bounds__(256) void attn_k(
    const unsigned short* __restrict__ qb, const unsigned short* __restrict__ kb,
    const unsigned short* __restrict__ vt, const unsigned short* __restrict__ lwh,
    unsigned short* __restrict__ ob)
{
    __shared__ unsigned short Qlds[64][72];
    __shared__ unsigned short Klds[64][72];
    __shared__ unsigned short Vlds[64][72];
    __shared__ unsigned short Plds[4][16][72];
    __shared__ unsigned short LWs[64][72];

    const int t = threadIdx.x;
    const int l = t & 63, wq = t >> 6;
    const int bx = blockIdx.x;
    const int qt = bx & 7, h = (bx >> 3) & 7, b = bx >> 6;
    const int q0 = qt << 6;
    const int sr = t >> 3, sc8 = (t & 7) << 3;
    const int lrow = l & 15, lgrp = l >> 4;
    const int qr0 = t >> 3, c80 = (t & 7) << 3;
    const int qr1 = 32 + (t >> 3), c81 = c80;

    const size_t lwb = ((size_t)(b * Hh + h) * Nn + q0) * Nn;

    // stage Q
#pragma unroll
    for (int it = 0; it < 2; ++it) {
        const int r = it * 32 + sr;
        *(u16x8*)&Qlds[r][sc8] =
            *(const u16x8*)(qb + (((size_t)b * Nn + q0 + r) * Hh + h) * DKk + sc8);
    }

    // chunk-0 registers + LDS write
    u16x8 kr[2], vr[2], lwr[2];
#pragma unroll
    for (int it = 0; it < 2; ++it) {
        const int r = it * 32 + sr;
        kr[it] = *(const u16x8*)(kb + (((size_t)b * Nn + r) * Hh + h) * DKk + sc8);
        vr[it] = *(const u16x8*)(vt + ((size_t)(b * Hh + h) * DKk + r) * Nn + sc8);
    }
    lwr[0] = *(const u16x8*)(lwh + lwb + (size_t)qr0 * Nn + c80);
    lwr[1] = *(const u16x8*)(lwh + lwb + (size_t)qr1 * Nn + c81);
#pragma unroll
    for (int it = 0; it < 2; ++it) {
        const int r = it * 32 + sr;
        *(u16x8*)&Klds[r][sc8] = kr[it];
        *(u16x8*)&Vlds[r][sc8] = vr[it];
    }
    *(u16x8*)&LWs[qr0][c80] = lwr[0];
    *(u16x8*)&LWs[qr1][c81] = lwr[1];
    __syncthreads();

    bf16x8 qa[2];
    qa[0] = *(const bf16x8*)&Qlds[wq * 16 + lrow][lgrp << 3];
    qa[1] = *(const bf16x8*)&Qlds[wq * 16 + lrow][32 + (lgrp << 3)];

    float m[4], lsum[4];
    f32x4 oacc[4];
#pragma unroll
    for (int r = 0; r < 4; ++r) { m[r] = -1e30f; lsum[r] = 0.f; }
#pragma unroll
    for (int fd = 0; fd < 4; ++fd) oacc[fd] = (f32x4){0.f, 0.f, 0.f, 0.f};

    for (int c = 0; c < 8; ++c) {
        if (c) __syncthreads();   // chunk c LDS writes visible
        if (c < 7) {              // prefetch chunk c+1 into registers
            const int k1 = (c + 1) << 6;
#pragma unroll
            for (int it = 0; it < 2; ++it) {
                const int r = it * 32 + sr;
                kr[it] = *(const u16x8*)(kb + (((size_t)b * Nn + k1 + r) * Hh + h) * DKk + sc8);
                vr[it] = *(const u16x8*)(vt + ((size_t)(b * Hh + h) * DKk + r) * Nn + k1 + sc8);
            }
            lwr[0] = *(const u16x8*)(lwh + lwb + (size_t)qr0 * Nn + k1 + c80);
            lwr[1] = *(const u16x8*)(lwh + lwb + (size_t)qr1 * Nn + k1 + c81);
        }

        // S = Q K^T
        f32x4 sacc[4];
#pragma unroll
        for (int f = 0; f < 4; ++f) sacc[f] = (f32x4){0.f, 0.f, 0.f, 0.f};
#pragma unroll
        for (int ks = 0; ks < 2; ++ks)
#pragma unroll
            for (int f = 0; f < 4; ++f) {
                const bf16x8 kf = *(const bf16x8*)&Klds[f * 16 + lrow][(ks << 5) + (lgrp << 3)];
                sacc[f] = __builtin_amdgcn_mfma_f32_16x16x32_bf16(qa[ks], kf, sacc[f], 0, 0, 0);
            }

        // logits + online softmax
        float p[4][4], mx[4];
#pragma unroll
        for (int r = 0; r < 4; ++r) mx[r] = -1e30f;
#pragma unroll
        for (int f = 0; f < 4; ++f) {
#pragma unroll
            for (int r = 0; r < 4; ++r) {
                const float lg = sacc[f][r] + h2f(LWs[wq * 16 + lgrp * 4 + r][f * 16 + lrow]);
                p[f][r] = lg;
                mx[r] = fmaxf(mx[r], lg);
            }
        }
#pragma unroll
        for (int r = 0; r < 4; ++r) {
            float cm = mx[r];
            cm = fmaxf(cm, __shfl_xor(cm, 1));
            cm = fmaxf(cm, __shfl_xor(cm, 2));
            cm = fmaxf(cm, __shfl_xor(cm, 4));
            cm = fmaxf(cm, __shfl_xor(cm, 8));
            const float mn = fmaxf(m[r], cm);
            const float sc = __expf(m[r] - mn);
            m[r] = mn;
            float ps = 0.f;
#pragma unroll
            for (int f = 0; f < 4; ++f) {
                p[f][r] = __expf(p[f][r] - mn);
                ps += p[f][r];
            }
            ps += __shfl_xor(ps, 1);
            ps += __shfl_xor(ps, 2);
            ps += __shfl_xor(ps, 4);
            ps += __shfl_xor(ps, 8);
            lsum[r] = lsum[r] * sc + ps;
#pragma unroll
            for (int fd = 0; fd < 4; ++fd) oacc[fd][r] *= sc;
        }

        // P -> per-wave LDS (wave-local, no barrier)
#pragma unroll
        for (int f = 0; f < 4; ++f)
#pragma unroll
            for (int r = 0; r < 4; ++r)
                Plds[wq][lgrp * 4 + r][f * 16 + lrow] = f2bf(p[f][r]);

        // O += P V
#pragma unroll
        for (int ks = 0; ks < 2; ++ks) {
            const bf16x8 pa = *(const bf16x8*)&Plds[wq][lrow][(ks << 5) + (lgrp << 3)];
#pragma unroll
            for (int fd = 0; fd < 4; ++fd) {
                const bf16x8 vf = *(const bf16x8*)&Vlds[fd * 16 + lrow][(ks << 5) + (lgrp << 3)];
                oacc[fd] = __builtin_amdgcn_mfma_f32_16x16x32_bf16(pa, vf, oacc[fd], 0, 0, 0);
            }
        }

        if (c < 7) {
            __syncthreads();      // everyone done reading chunk c
#pragma unroll
            for (int it = 0; it < 2; ++it) {
                const int r = it * 32 + sr;
                *(u16x8*)&Klds[r][sc8] = kr[it];
                *(u16x8*)&Vlds[r][sc8] = vr[it];
            }
            *(u16x8*)&LWs[qr0][c80] = lwr[0];
            *(u16x8*)&LWs[qr1][c81] = lwr[1];
        }
    }

    // epilogue: normalize, write ob bf16 [b,n,h,d]
#pragma unroll
    for (int r = 0; r < 4; ++r) {
        const float inv = 1.0f / lsum[r];
        const int qrow = q0 + wq * 16 + lgrp * 4 + r;
#pragma unroll
        for (int fd = 0; fd < 4; ++fd) {
            ob[(((size_t)b * Nn + qrow) * Hh + h) * DKk + fd * 16 + lrow] =
                f2bf(oacc[fd][r] * inv);
        }
    }
}

// ---------------------------------------------------------------------------
// Output projection: C[2048,512] fp32 = A(bf16) @ Wo(fp32, column-loaded) + bo
// ---------------------------------------------------------------------------
__global__ __launch_bounds__(256) void outproj_k(
    const unsigned short* __restrict__ A, const float* __restrict__ W,
    const float* __restrict__ bias, float* __restrict__ C)
{
    __shared__ unsigned short Alds[64][40];
    __shared__ unsigned short Blds[64][40];
    const int t = threadIdx.x;
    const int l = t & 63, wq = t >> 6;
    const int col0 = (int)(blockIdx.x) << 6, row0 = (int)(blockIdx.y) << 6;
    const int lr = t >> 2, lc8 = (t & 3) << 3;
    const int bn = t & 63, bk8 = (t >> 6) << 3;
    const int lrow = l & 15, lgrp = l >> 4;

    f32x4 acc[4];
#pragma unroll
    for (int nf = 0; nf < 4; ++nf) acc[nf] = (f32x4){0.f, 0.f, 0.f, 0.f};

    for (int k0 = 0; k0 < Dd; k0 += 32) {
        const u16x8 a8 = *(const u16x8*)(A + (size_t)(row0 + lr) * Dd + k0 + lc8);
        u16x8 b8;
#pragma unroll
        for (int jj = 0; jj < 8; ++jj)
            b8[jj] = f2bf(W[(size_t)(k0 + bk8 + jj) * Dd + col0 + bn]);
        __syncthreads();
        *(u16x8*)&Alds[lr][lc8] = a8;
        *(u16x8*)&Blds[bn][bk8] = b8;
        __syncthreads();
        const bf16x8 a = *(const bf16x8*)&Alds[wq * 16 + lrow][lgrp << 3];
#pragma unroll
        for (int nf = 0; nf < 4; ++nf) {
            const bf16x8 bfr = *(const bf16x8*)&Blds[nf * 16 + lrow][lgrp << 3];
            acc[nf] = __builtin_amdgcn_mfma_f32_16x16x32_bf16(a, bfr, acc[nf], 0, 0, 0);
        }
    }

    const int rbase = row0 + wq * 16 + (lgrp << 2);
#pragma unroll
    for (int nf = 0; nf < 4; ++nf) {
        const int colg = col0 + nf * 16 + lrow;
        const float bv = bias[colg];
#pragma unroll
        for (int r = 0; r < 4; ++r)
            C[(size_t)(rbase + r) * Dd + colg] = acc[nf][r] + bv;
    }
}

// ---------------------------------------------------------------------------
extern "C" void kernel_launch(void* const* d_in, const int* in_sizes, int n_in,
                              void* d_out, int out_size, void* d_ws, size_t ws_size,
                              hipStream_t stream)
{
    (void)in_sizes; (void)n_in; (void)out_size; (void)ws_size;

    const float* q_in = (const float*)d_in[0];
    const float* k_in = (const float*)d_in[1];
    const float* v_in = (const float*)d_in[2];
    const float* box  = (const float*)d_in[3];
    const int*   mask = (const int*)d_in[4];
    const float* Wq = (const float*)d_in[5];
    const float* bq = (const float*)d_in[6];
    const float* Wk = (const float*)d_in[7];
    const float* bk = (const float*)d_in[8];
    const float* Wv = (const float*)d_in[9];
    const float* bv = (const float*)d_in[10];
    const float* Wo = (const float*)d_in[11];
    const float* bo = (const float*)d_in[12];
    const float* Wg = (const float*)d_in[13];
    const float* bg = (const float*)d_in[14];
    float* out = (float*)d_out;

    char* ws = (char*)d_ws;
    unsigned short* qb  = (unsigned short*)(ws);                 // 2 MB  [b,n,h,d] bf16 (pre-scaled 1/8)
    unsigned short* kb  = (unsigned short*)(ws + (2u << 20));    // 2 MB  [b,n,h,d] bf16
    unsigned short* vt  = (unsigned short*)(ws + (4u << 20));    // 2 MB  [b,h,d,n] bf16
    unsigned short* ob  = (unsigned short*)(ws + (6u << 20));    // 2 MB  [b,n,h,d] bf16
    unsigned short* lwh = (unsigned short*)(ws + (8u << 20));    // 16 MB [b,h,i,j] fp16

    // 1) merged geo + QKV projections
    PreArgs pa;
    pa.A[0] = q_in; pa.A[1] = k_in; pa.A[2] = v_in;
    pa.W[0] = Wq;   pa.W[1] = Wk;   pa.W[2] = Wv;
    pa.bias[0] = bq; pa.bias[1] = bk; pa.bias[2] = bv;
    pa.C[0] = qb; pa.C[1] = kb; pa.C[2] = vt;
    pa.ns[0] = Dd; pa.ns[1] = Dd; pa.ns[2] = 1;
    pa.cs[0] = 1;  pa.cs[1] = 1;  pa.cs[2] = Nn;
    pa.scale[0] = 0.125f; pa.scale[1] = 1.0f; pa.scale[2] = 1.0f;
    pa.box = box; pa.mask = mask; pa.Wg = Wg; pa.bg = bg; pa.lw = lwh;
    pre_k<<<dim3(4864), 256, 0, stream>>>(pa);

    // 2) fused attention
    attn_k<<<dim3(Bq * Hh * (Nn / 64)), 256, 0, stream>>>(qb, kb, vt, lwh, ob);

    // 3) output projection
    outproj_k<<<dim3(8, 32), 256, 0, stream>>>(ob, Wo, bo, out);
}